// Round 2
// baseline (271.177 us; speedup 1.0000x reference)
//
#include <hip/hip_runtime.h>
#include <hip/hip_bf16.h>
#include <stdint.h>

// Shapes (fixed by the problem)
//   x: (4,2048,1024) f32; Wq/Wk/Wv: (1024,1024) f32; out: (4,2048,1024) f32
// Pipeline: cvt->bf16 | QKV NT-GEMMs (V stored transposed) | QK^T *1/32 -> f32
//           | row softmax -> bf16 P | P@V^T -> f32 out

typedef short bf16x8 __attribute__((ext_vector_type(8)));
typedef float f32x4  __attribute__((ext_vector_type(4)));
typedef unsigned short ushortx8 __attribute__((ext_vector_type(8)));

__device__ __forceinline__ unsigned short f2bf(float f) {
  unsigned u = __float_as_uint(f);
  u += 0x7fff + ((u >> 16) & 1);   // RNE; inputs are finite
  return (unsigned short)(u >> 16);
}

__global__ __launch_bounds__(256) void cvt_bf16(const float* __restrict__ src,
                                                unsigned short* __restrict__ dst) {
  int i = (blockIdx.x * 256 + threadIdx.x) * 4;
  float4 v = *(const float4*)(src + i);
  ushort4 o;
  o.x = f2bf(v.x); o.y = f2bf(v.y); o.z = f2bf(v.z); o.w = f2bf(v.w);
  *(ushort4*)(dst + i) = o;
}

__device__ __forceinline__ void gload_lds16(const void* g, void* l) {
  __builtin_amdgcn_global_load_lds(
      (const __attribute__((address_space(1))) unsigned int*)g,
      (__attribute__((address_space(3))) unsigned int*)l, 16, 0, 0);
}

// NT GEMM: C[m][n] = scale * sum_k A[m][k]*B[n][k]; A,B bf16 row-major K-contig.
// Tile 128x128, BK=32, 4 waves (2x2 of 64x64), 16x16x32 MFMA.
// LDS chunk swizzle: 16B chunk kg stored at kg ^ ((row>>1)&3) -> ds_read_b128 2-way (free).
// STORE: 0 = bf16 row-major (+bz*strideC)
//        1 = f32 row-major (+bz*strideC), scaled
//        2 = bf16 transposed per 2048-row batch: C[((r>>11)*1024 + c)*2048 + (r&2047)]
template<int STORE>
__global__ __launch_bounds__(256, 2) void gemm_nt(
    const unsigned short* __restrict__ A, const unsigned short* __restrict__ B,
    void* __restrict__ Cv, int lda, int ldb, int ldc, int K,
    long strideA, long strideB, long strideC, float scale) {
  __shared__ __align__(16) unsigned short lds[2][2][128 * 32];
  const int tid  = threadIdx.x;
  const int lane = tid & 63;
  const int wid  = tid >> 6;
  const int bz   = blockIdx.z;
  const unsigned short* Ab = A + (size_t)bz * strideA;
  const unsigned short* Bb = B + (size_t)bz * strideB;
  const int row0 = blockIdx.x * 128;
  const int col0 = blockIdx.y * 128;

  f32x4 acc[4][4];
#pragma unroll
  for (int m = 0; m < 4; ++m)
#pragma unroll
    for (int n = 0; n < 4; ++n) acc[m][n] = f32x4{0.f, 0.f, 0.f, 0.f};

  const int KT = K >> 5;

  auto stage = [&](int buf, int kt) {
    const int k0 = kt << 5;
#pragma unroll
    for (int it = 0; it < 2; ++it) {
      int j   = it * 256 + tid;       // 512 chunks of 16B per operand tile
      int r   = j >> 2;               // tile row 0..127
      int kg  = j & 3;                // 16B chunk within row
      int kgS = kg ^ ((r >> 1) & 3);  // pre-swizzled global source (LDS stays linear)
      gload_lds16(Ab + (size_t)(row0 + r) * lda + k0 + kgS * 8, &lds[buf][0][j * 8]);
      gload_lds16(Bb + (size_t)(col0 + r) * ldb + k0 + kgS * 8, &lds[buf][1][j * 8]);
    }
  };

  stage(0, 0);
  int buf = 0;
  for (int kt = 0; kt < KT; ++kt) {
    __syncthreads();  // drains vmcnt for staged buf; also guards re-stage of the other buf
    if (kt + 1 < KT) stage(buf ^ 1, kt + 1);
    const unsigned short* As = &lds[buf][0][0];
    const unsigned short* Bs = &lds[buf][1][0];
    const int kg = lane >> 4;
    const int lr = lane & 15;
    bf16x8 af[4], bfr[4];
#pragma unroll
    for (int m = 0; m < 4; ++m) {
      int r = ((wid >> 1) * 64) + m * 16 + lr;
      af[m] = *(const bf16x8*)(As + r * 32 + ((kg ^ ((r >> 1) & 3)) * 8));
    }
#pragma unroll
    for (int n = 0; n < 4; ++n) {
      int c = ((wid & 1) * 64) + n * 16 + lr;
      bfr[n] = *(const bf16x8*)(Bs + c * 32 + ((kg ^ ((c >> 1) & 3)) * 8));
    }
#pragma unroll
    for (int m = 0; m < 4; ++m)
#pragma unroll
      for (int n = 0; n < 4; ++n)
        acc[m][n] = __builtin_amdgcn_mfma_f32_16x16x32_bf16(af[m], bfr[n], acc[m][n], 0, 0, 0);
    buf ^= 1;
  }

  // Epilogue. C/D layout: col = lane&15, row = (lane>>4)*4 + j  [m89-verified]
  const int wr0 = row0 + (wid >> 1) * 64;
  const int wc0 = col0 + (wid & 1) * 64;
  const int rj  = lane >> 4;
  const int cl  = lane & 15;
#pragma unroll
  for (int m = 0; m < 4; ++m) {
#pragma unroll
    for (int n = 0; n < 4; ++n) {
#pragma unroll
      for (int j = 0; j < 4; ++j) {
        int r = wr0 + m * 16 + rj * 4 + j;
        int c = wc0 + n * 16 + cl;
        float val = acc[m][n][j];
        if constexpr (STORE == 0) {
          unsigned short* C = (unsigned short*)Cv + (size_t)bz * strideC;
          C[(size_t)r * ldc + c] = f2bf(val);
        } else if constexpr (STORE == 1) {
          float* C = (float*)Cv + (size_t)bz * strideC;
          C[(size_t)r * ldc + c] = val * scale;
        } else {
          unsigned short* C = (unsigned short*)Cv;
          size_t idx = ((size_t)(r >> 11) * 1024 + c) * 2048 + (size_t)(r & 2047);
          C[idx] = f2bf(val);
        }
      }
    }
  }
}

// One block per row of 2048 f32 scores -> bf16 probabilities.
__global__ __launch_bounds__(256) void softmax_rows(const float* __restrict__ S,
                                                    unsigned short* __restrict__ P) {
  const size_t row = blockIdx.x;
  const float* s = S + row * 2048;
  unsigned short* p = P + row * 2048;
  const int tid  = threadIdx.x;
  const int lane = tid & 63;
  const int wid  = tid >> 6;
  float4 a = *(const float4*)(s + tid * 8);
  float4 b = *(const float4*)(s + tid * 8 + 4);
  float v[8] = {a.x, a.y, a.z, a.w, b.x, b.y, b.z, b.w};
  float mx = v[0];
#pragma unroll
  for (int i = 1; i < 8; ++i) mx = fmaxf(mx, v[i]);
#pragma unroll
  for (int o = 1; o < 64; o <<= 1) mx = fmaxf(mx, __shfl_xor(mx, o));
  __shared__ float redm[4], reds[4];
  if (lane == 0) redm[wid] = mx;
  __syncthreads();
  mx = fmaxf(fmaxf(redm[0], redm[1]), fmaxf(redm[2], redm[3]));
  float sum = 0.f;
#pragma unroll
  for (int i = 0; i < 8; ++i) { v[i] = __expf(v[i] - mx); sum += v[i]; }
#pragma unroll
  for (int o = 1; o < 64; o <<= 1) sum += __shfl_xor(sum, o);
  if (lane == 0) reds[wid] = sum;
  __syncthreads();
  sum = (reds[0] + reds[1]) + (reds[2] + reds[3]);
  float inv = 1.f / sum;
  ushortx8 o8;
#pragma unroll
  for (int i = 0; i < 8; ++i) o8[i] = f2bf(v[i] * inv);
  *(ushortx8*)(p + tid * 8) = o8;
}

extern "C" void kernel_launch(void* const* d_in, const int* in_sizes, int n_in,
                              void* d_out, int out_size, void* d_ws, size_t ws_size,
                              hipStream_t stream) {
  const float* x  = (const float*)d_in[0];
  const float* Wq = (const float*)d_in[1];
  const float* Wk = (const float*)d_in[2];
  const float* Wv = (const float*)d_in[3];

  char* w = (char*)d_ws;
  // ws layout (bytes): xb 16M | Wq,Wk 4M | Wv 2M | Q,K 32M | Vt 16M | P 32M | Sc 64M = 166M
  unsigned short* xb  = (unsigned short*)(w);
  unsigned short* wqk = (unsigned short*)(w + (16ull << 20));
  unsigned short* wv  = (unsigned short*)(w + (20ull << 20));
  unsigned short* QK  = (unsigned short*)(w + (22ull << 20));  // Q then K, 8M elems each
  unsigned short* Vt  = (unsigned short*)(w + (54ull << 20));  // [b][o][s]
  unsigned short* P   = (unsigned short*)(w + (70ull << 20));  // [b][q][k] bf16
  float*          Sc  = (float*)        (w + (102ull << 20));  // [b][q][k] f32

  // fp32 -> bf16
  cvt_bf16<<<8192, 256, 0, stream>>>(x,  xb);
  cvt_bf16<<<1024, 256, 0, stream>>>(Wq, wqk);
  cvt_bf16<<<1024, 256, 0, stream>>>(Wk, wqk + (1u << 20));
  cvt_bf16<<<1024, 256, 0, stream>>>(Wv, wv);

  // Q = x@Wq^T, K = x@Wk^T (z picks weight/output)
  gemm_nt<0><<<dim3(64, 8, 2), 256, 0, stream>>>(
      xb, wqk, QK, 1024, 1024, 1024, 1024, 0, 1ll << 20, 8ll << 20, 1.f);
  // V^T = (x@Wv^T)^T, stored [b][o][s]
  gemm_nt<2><<<dim3(64, 8, 1), 256, 0, stream>>>(
      xb, wv, Vt, 1024, 1024, 0, 1024, 0, 0, 0, 1.f);
  // scores = (Q@K^T) / 32 per batch, f32
  gemm_nt<1><<<dim3(16, 16, 4), 256, 0, stream>>>(
      QK, QK + (8u << 20), Sc, 1024, 1024, 2048, 1024,
      2ll << 20, 2ll << 20, 4ll << 20, 0.03125f);
  // row softmax -> bf16 P
  softmax_rows<<<8192, 256, 0, stream>>>(Sc, P);
  // out = P @ V^T (f32 straight to d_out)
  gemm_nt<1><<<dim3(16, 8, 4), 256, 0, stream>>>(
      P, Vt, d_out, 2048, 2048, 1024, 2048,
      4ll << 20, 2ll << 20, 2ll << 20, 1.f);
}